// Round 1
// baseline (166.306 us; speedup 1.0000x reference)
//
#include <hip/hip_runtime.h>
#include <hip/hip_bf16.h>

typedef __attribute__((ext_vector_type(8))) short short8;
typedef __attribute__((ext_vector_type(4))) float f32x4;

#define B_ 8
#define N_ 4096
#define E_ 16384
#define K_ 16
#define F_ 128

__device__ __forceinline__ float bf2f(unsigned short h) {
    unsigned int u = ((unsigned int)h) << 16;
    union { unsigned int u; float f; } c; c.u = u; return c.f;
}
__device__ __forceinline__ unsigned short f2bf(float f) {
    union { float f; unsigned int u; } c; c.f = f;
    unsigned int u = c.u;
    unsigned int r = (u + 0x7fffu + ((u >> 16) & 1u)) >> 16;
    return (unsigned short)r;
}

// ---- detect whether an "integer" input buffer is int64 (high words all 0) ----
__device__ __forceinline__ int detect64(const int* raw) {
    int o = 0;
    #pragma unroll
    for (int i = 1; i < 128; i += 2) o |= raw[i];
    return (o == 0) ? 1 : 0;
}

// sender[i] = edges[b,e,0]  (stride 3), handling int32 or int64 source
__global__ void conv_sender(const int* __restrict__ raw, int* __restrict__ dst) {
    __shared__ int s64;
    if (threadIdx.x == 0) s64 = detect64(raw);
    __syncthreads();
    int i = blockIdx.x * 256 + threadIdx.x;
    if (i < B_ * E_) {
        dst[i] = s64 ? raw[6 * (long long)i] : raw[3 * (long long)i];
    }
}

// node_edges flat copy, handling int32 or int64 source
__global__ void conv_ne(const int* __restrict__ raw, int* __restrict__ dst) {
    __shared__ int s64;
    if (threadIdx.x == 0) s64 = detect64(raw);
    __syncthreads();
    int i = blockIdx.x * 256 + threadIdx.x;
    if (i < B_ * N_ * K_) {
        dst[i] = s64 ? raw[2 * (long long)i] : raw[i];
    }
}

// Pre-swizzle W1,W2 into MFMA B-fragment order (bf16).
// For mfma_f32_16x16x32_bf16, B operand: lane l holds B[8*(l>>4)+t][l&15], t=0..7
// with B[k][j] = W[j][k].  Layout: wf[((nt*4+g)*64 + lane)*8 + t]
__global__ void wprep(const float* __restrict__ W1, const float* __restrict__ W2,
                      unsigned short* __restrict__ wf) {
    int tid = blockIdx.x * 256 + threadIdx.x;  // 0..4095
    int wsel = tid >> 11;
    int q = tid & 2047;
    int lane = q & 63;
    int gq = q >> 6;          // nt*4+g
    int nt = gq >> 2, g = gq & 3;
    const float* W = wsel ? W2 : W1;
    int j = nt * 16 + (lane & 15);
    int kbase = g * 32 + 8 * (lane >> 4);
    unsigned short* d = wf + wsel * 16384 + q * 8;
    #pragma unroll
    for (int t = 0; t < 8; ++t) d[t] = f2bf(W[j * 128 + kbase + t]);
}

// x0 -> out[:, :, 0:128] (fp32) and xb (bf16)
__global__ void prep_x0(const float* __restrict__ x0, float* __restrict__ out,
                        unsigned short* __restrict__ xb) {
    long long gid = (long long)blockIdx.x * 256 + threadIdx.x;  // < B*N*F/4
    long long flat = gid * 4;
    long long bn = flat >> 7;
    int j = (int)(flat & 127);
    float4 v = *(const float4*)(x0 + flat);
    *(float4*)(out + bn * 384 + j) = v;
    ushort4 h;
    h.x = f2bf(v.x); h.y = f2bf(v.y); h.z = f2bf(v.z); h.w = f2bf(v.w);
    *(ushort4*)(xb + flat) = h;
}

// edge_emb[b,e,:] = bf16( tanh( x[b,sender(e),:] @ W^T + bias ) )
// 64 edges per block, 4 waves; MFMA 16x16x32 bf16.
__global__ void __launch_bounds__(256) edge_kernel(
    const unsigned short* __restrict__ xb, const int* __restrict__ sender,
    const unsigned short* __restrict__ wf, const float* __restrict__ bias,
    unsigned short* __restrict__ eout) {
    __shared__ short xt[64 * F_];   // 16 KB, chunk-swizzled
    __shared__ int sids[64];
    int tid = threadIdx.x;
    int blk = blockIdx.x;
    int b = (blk * 64) / E_;
    int e0 = (blk * 64) % E_;
    if (tid < 64) sids[tid] = sender[b * E_ + e0 + tid];
    __syncthreads();
    // gather 64 rows (256B bf16 each) into LDS; swizzle 16B chunks: pch = ch ^ (row&15)
    #pragma unroll
    for (int c = 0; c < 4; ++c) {
        int ci = tid + 256 * c;         // 0..1023
        int row = ci >> 4, ch = ci & 15;
        int pch = ch ^ (row & 15);
        const int4* src = (const int4*)(xb + ((long long)(b * N_ + sids[row])) * F_ + ch * 8);
        *(int4*)&xt[row * F_ + pch * 8] = *src;
    }
    __syncthreads();
    int w = tid >> 6, lane = tid & 63;
    int rbase = w * 16;
    // A fragments: lane l holds A[rbase + (l&15)][8*(l>>4)+t + 32*g]
    short8 afr[4];
    #pragma unroll
    for (int g = 0; g < 4; ++g) {
        int row = rbase + (lane & 15);
        int pch = (g * 4 + (lane >> 4)) ^ (row & 15);
        afr[g] = *(const short8*)&xt[row * F_ + pch * 8];
    }
    f32x4 acc[8];
    #pragma unroll
    for (int nt = 0; nt < 8; ++nt) acc[nt] = (f32x4){0.f, 0.f, 0.f, 0.f};
    #pragma unroll
    for (int nt = 0; nt < 8; ++nt) {
        #pragma unroll
        for (int g = 0; g < 4; ++g) {
            short8 bfr = *(const short8*)(wf + ((nt * 4 + g) * 64 + lane) * 8);
            acc[nt] = __builtin_amdgcn_mfma_f32_16x16x32_bf16(afr[g], bfr, acc[nt], 0, 0, 0);
        }
    }
    // epilogue: C/D layout col=lane&15, row=(lane>>4)*4+reg
    int colb = lane & 15;
    int rloc = rbase + (lane >> 4) * 4;
    #pragma unroll
    for (int nt = 0; nt < 8; ++nt) {
        int col = nt * 16 + colb;
        float bv = bias[col];
        #pragma unroll
        for (int r = 0; r < 4; ++r) {
            float v = tanhf(acc[nt][r] + bv);
            eout[((long long)(b * E_ + e0 + rloc + r)) * F_ + col] = f2bf(v);
        }
    }
}

// x_next[b,n,:] = sum_k mask * edge_emb[b, ne[n,k], :] / (cnt + eps)
// one wave per node; lane covers cols {2l, 2l+1}
__global__ void __launch_bounds__(256) agg_kernel(
    const unsigned short* __restrict__ ee, const int* __restrict__ ne,
    const int* __restrict__ mk, float* __restrict__ out,
    unsigned short* __restrict__ xbn, int col_off) {
    int wid = threadIdx.x >> 6, lane = threadIdx.x & 63;
    long long node = (long long)blockIdx.x * 4 + wid;  // < B*N
    int b = (int)(node >> 12);                          // N=4096
    const int* nep = ne + node * K_;
    const int* mkp = mk + node * K_;
    float ax = 0.f, ay = 0.f;
    int cnt = 0;
    const unsigned short* ebase = ee + (long long)b * E_ * F_ + lane * 2;
    #pragma unroll
    for (int k = 0; k < K_; ++k) {
        int m = mkp[k];         // wave-uniform -> execz skip when masked
        if (m) {
            int eid = nep[k];
            unsigned int v = *(const unsigned int*)(ebase + (long long)eid * F_);
            ax += bf2f((unsigned short)(v & 0xffffu));
            ay += bf2f((unsigned short)(v >> 16));
            cnt++;
        }
    }
    float inv = 1.0f / ((float)cnt + 1e-8f);
    ax *= inv; ay *= inv;
    float2 o; o.x = ax; o.y = ay;
    *(float2*)(out + node * 384 + col_off + lane * 2) = o;
    if (xbn) {
        unsigned int p = ((unsigned int)f2bf(ay) << 16) | (unsigned int)f2bf(ax);
        *(unsigned int*)(xbn + node * F_ + lane * 2) = p;
    }
}

extern "C" void kernel_launch(void* const* d_in, const int* in_sizes, int n_in,
                              void* d_out, int out_size, void* d_ws, size_t ws_size,
                              hipStream_t stream) {
    const float* x0        = (const float*)d_in[0];
    const int*   edges_raw = (const int*)d_in[1];
    const int*   ne_raw    = (const int*)d_in[2];
    const int*   mask      = (const int*)d_in[3];
    const float* W1        = (const float*)d_in[4];
    const float* b1        = (const float*)d_in[5];
    const float* W2        = (const float*)d_in[6];
    const float* b2        = (const float*)d_in[7];
    float* out = (float*)d_out;
    char* ws = (char*)d_ws;

    unsigned short* xb   = (unsigned short*)ws;                   // B*N*F bf16   = 8 MB
    unsigned short* ebuf = (unsigned short*)(ws + 8388608);       // B*E*F bf16   = 32 MB
    unsigned short* wf   = (unsigned short*)(ws + 41943040);      // 2*128*128    = 64 KB
    int* sender32        = (int*)(ws + 42008576);                 // B*E int32    = 512 KB
    int* ne32            = (int*)(ws + 42532864);                 // B*N*K int32  = 2 MB

    conv_sender<<<512, 256, 0, stream>>>(edges_raw, sender32);
    conv_ne<<<2048, 256, 0, stream>>>(ne_raw, ne32);
    wprep<<<16, 256, 0, stream>>>(W1, W2, wf);
    prep_x0<<<4096, 256, 0, stream>>>(x0, out, xb);

    // round 1
    edge_kernel<<<2048, 256, 0, stream>>>(xb, sender32, wf, b1, ebuf);
    agg_kernel<<<8192, 256, 0, stream>>>(ebuf, ne32, mask, out, xb, 128);
    // round 2
    edge_kernel<<<2048, 256, 0, stream>>>(xb, sender32, wf + 16384, b2, ebuf);
    agg_kernel<<<8192, 256, 0, stream>>>(ebuf, ne32, mask, out, nullptr, 256);
}

// Round 2
// 101.861 us; speedup vs baseline: 1.6327x; 1.6327x over previous
//
#include <hip/hip_runtime.h>
#include <hip/hip_bf16.h>

typedef __attribute__((ext_vector_type(8))) short short8;
typedef __attribute__((ext_vector_type(4))) float f32x4;

#define B_ 8
#define N_ 4096
#define E_ 16384
#define K_ 16
#define F_ 128

__device__ __forceinline__ float bf2f(unsigned short h) {
    unsigned int u = ((unsigned int)h) << 16;
    union { unsigned int u; float f; } c; c.u = u; return c.f;
}
__device__ __forceinline__ unsigned short f2bf(float f) {
    union { float f; unsigned int u; } c; c.f = f;
    unsigned int u = c.u;
    unsigned int r = (u + 0x7fffu + ((u >> 16) & 1u)) >> 16;
    return (unsigned short)r;
}
__device__ __forceinline__ float fast_tanh(float x) {
    // tanh(x) = 1 - 2/(exp(2x)+1); exact limits at +-inf, ~1e-7 rel err
    float e = __expf(2.0f * x);
    return 1.0f - 2.0f / (e + 1.0f);
}

// ---- detect whether an "integer" input buffer is int64 (high words all 0) ----
__device__ __forceinline__ int detect64(const int* raw) {
    int o = 0;
    #pragma unroll
    for (int i = 1; i < 128; i += 2) o |= raw[i];
    return (o == 0) ? 1 : 0;
}

// sender[i] = edges[b,e,0]  (stride 3), handling int32 or int64 source
__global__ void conv_sender(const int* __restrict__ raw, int* __restrict__ dst) {
    __shared__ int s64;
    if (threadIdx.x == 0) s64 = detect64(raw);
    __syncthreads();
    int i = blockIdx.x * 256 + threadIdx.x;
    if (i < B_ * E_) {
        dst[i] = s64 ? raw[6 * (long long)i] : raw[3 * (long long)i];
    }
}

// pne[i] = mask[i] ? node_edges[i] : -1   (handles int32/int64 node_edges)
__global__ void conv_ne(const int* __restrict__ raw, const int* __restrict__ mask,
                        int* __restrict__ pne) {
    __shared__ int s64;
    if (threadIdx.x == 0) s64 = detect64(raw);
    __syncthreads();
    int i = blockIdx.x * 256 + threadIdx.x;
    if (i < B_ * N_ * K_) {
        int eid = s64 ? raw[2 * (long long)i] : raw[i];
        pne[i] = mask[i] ? eid : -1;
    }
}

// Pre-swizzle W1,W2 into MFMA A-fragment order (bf16).
// A-operand of mfma_f32_16x16x32_bf16: lane l holds A[l&15][8*(l>>4)+t].
// With A = W tile (rows j, cols k): wf[((nt*4+g)*64+lane)*8+t]
//   = W[nt*16 + (lane&15)][g*32 + 8*(lane>>4) + t]
__global__ void wprep(const float* __restrict__ W1, const float* __restrict__ W2,
                      unsigned short* __restrict__ wf) {
    int tid = blockIdx.x * 256 + threadIdx.x;  // 0..4095
    int wsel = tid >> 11;
    int q = tid & 2047;
    int lane = q & 63;
    int gq = q >> 6;          // nt*4+g
    int nt = gq >> 2, g = gq & 3;
    const float* W = wsel ? W2 : W1;
    int j = nt * 16 + (lane & 15);
    int kbase = g * 32 + 8 * (lane >> 4);
    unsigned short* d = wf + wsel * 16384 + q * 8;
    #pragma unroll
    for (int t = 0; t < 8; ++t) d[t] = f2bf(W[j * 128 + kbase + t]);
}

// x0 -> out[:, :, 0:128] (fp32) and xb (bf16)
__global__ void prep_x0(const float* __restrict__ x0, float* __restrict__ out,
                        unsigned short* __restrict__ xb) {
    long long gid = (long long)blockIdx.x * 256 + threadIdx.x;  // < B*N*F/4
    long long flat = gid * 4;
    long long bn = flat >> 7;
    int j = (int)(flat & 127);
    float4 v = *(const float4*)(x0 + flat);
    *(float4*)(out + bn * 384 + j) = v;
    ushort4 h;
    h.x = f2bf(v.x); h.y = f2bf(v.y); h.z = f2bf(v.z); h.w = f2bf(v.w);
    *(ushort4*)(xb + flat) = h;
}

// edge_emb[b,e,:] = bf16( tanh( x[b,sender(e),:] @ W^T + bias ) )
// 64 edges/block, 4 waves. Swapped operands: A=W, B=x^T -> D[j][edge],
// lane's 4 acc regs are consecutive j -> 8B ushort4 stores.
__global__ void __launch_bounds__(256) edge_kernel(
    const unsigned short* __restrict__ xb, const int* __restrict__ sender,
    const unsigned short* __restrict__ wf, const float* __restrict__ bias,
    unsigned short* __restrict__ eout) {
    __shared__ short xt[64 * F_];   // 16 KB, chunk-swizzled
    __shared__ int sids[64];
    int tid = threadIdx.x;
    int blk = blockIdx.x;
    int b = (blk * 64) / E_;
    int e0 = (blk * 64) % E_;
    if (tid < 64) sids[tid] = sender[b * E_ + e0 + tid];
    __syncthreads();
    // gather 64 rows (256B bf16 each) into LDS; swizzle 16B chunks: pch = ch ^ (row&15)
    #pragma unroll
    for (int c = 0; c < 4; ++c) {
        int ci = tid + 256 * c;         // 0..1023
        int row = ci >> 4, ch = ci & 15;
        int pch = ch ^ (row & 15);
        const int4* src = (const int4*)(xb + ((long long)(b * N_ + sids[row])) * F_ + ch * 8);
        *(int4*)&xt[row * F_ + pch * 8] = *src;
    }
    __syncthreads();
    int w = tid >> 6, lane = tid & 63;
    int erow = w * 16 + (lane & 15);      // this wave's 16 edges
    // B fragments (x^T): lane holds x[erow][g*32 + 8*(lane>>4) + t]
    short8 bfr[4];
    #pragma unroll
    for (int g = 0; g < 4; ++g) {
        int pch = (g * 4 + (lane >> 4)) ^ (erow & 15);
        bfr[g] = *(const short8*)&xt[erow * F_ + pch * 8];
    }
    int jq = (lane >> 4) * 4;             // j sub-offset of this lane's 4 regs
    long long ebase = ((long long)(b * E_ + e0 + w * 16 + (lane & 15))) * F_;
    #pragma unroll
    for (int nt = 0; nt < 8; ++nt) {
        f32x4 acc = (f32x4){0.f, 0.f, 0.f, 0.f};
        #pragma unroll
        for (int g = 0; g < 4; ++g) {
            short8 afr = *(const short8*)(wf + ((nt * 4 + g) * 64 + lane) * 8);
            acc = __builtin_amdgcn_mfma_f32_16x16x32_bf16(afr, bfr[g], acc, 0, 0, 0);
        }
        float4 bv = *(const float4*)(bias + nt * 16 + jq);
        ushort4 o;
        o.x = f2bf(fast_tanh(acc[0] + bv.x));
        o.y = f2bf(fast_tanh(acc[1] + bv.y));
        o.z = f2bf(fast_tanh(acc[2] + bv.z));
        o.w = f2bf(fast_tanh(acc[3] + bv.w));
        *(ushort4*)(eout + ebase + nt * 16 + jq) = o;
    }
}

// x_next[b,n,:] = sum_k mask * edge_emb[b, ne[n,k], :] / (cnt + eps)
// one wave per node; half-wave k-split: lanes 0-31 even k, 32-63 odd k;
// each lane covers 4 cols (8B). Branchless (masked-out -> weight 0, edge 0).
__global__ void __launch_bounds__(256) agg_kernel(
    const unsigned short* __restrict__ ee, const int* __restrict__ pne,
    float* __restrict__ out, unsigned short* __restrict__ xbn, int col_off) {
    int wid = threadIdx.x >> 6, lane = threadIdx.x & 63;
    int node = blockIdx.x * 4 + wid;   // < B*N
    int b = node >> 12;                // N=4096
    const int4* q = (const int4*)(pne + node * K_);
    int4 q0 = q[0], q1 = q[1], q2 = q[2], q3 = q[3];
    int half = lane >> 5, sub = lane & 31;
    float cntf = (float)((q0.x >= 0) + (q0.y >= 0) + (q0.z >= 0) + (q0.w >= 0) +
                         (q1.x >= 0) + (q1.y >= 0) + (q1.z >= 0) + (q1.w >= 0) +
                         (q2.x >= 0) + (q2.y >= 0) + (q2.z >= 0) + (q2.w >= 0) +
                         (q3.x >= 0) + (q3.y >= 0) + (q3.z >= 0) + (q3.w >= 0));
    const unsigned short* ebase = ee + (long long)b * (E_ * F_) + sub * 4;
    float a0 = 0.f, a1 = 0.f, a2 = 0.f, a3 = 0.f;
    #define PROC(pe, po) { \
        int pk = half ? (po) : (pe); \
        float m = (pk >= 0) ? 1.0f : 0.0f; \
        int eid = pk < 0 ? 0 : pk; \
        ushort4 v = *(const ushort4*)(ebase + (long long)eid * F_); \
        a0 += m * bf2f(v.x); a1 += m * bf2f(v.y); \
        a2 += m * bf2f(v.z); a3 += m * bf2f(v.w); }
    PROC(q0.x, q0.y) PROC(q0.z, q0.w)
    PROC(q1.x, q1.y) PROC(q1.z, q1.w)
    PROC(q2.x, q2.y) PROC(q2.z, q2.w)
    PROC(q3.x, q3.y) PROC(q3.z, q3.w)
    #undef PROC
    // combine even/odd halves (partner lane has same cols)
    a0 += __shfl_xor(a0, 32);
    a1 += __shfl_xor(a1, 32);
    a2 += __shfl_xor(a2, 32);
    a3 += __shfl_xor(a3, 32);
    if (half == 0) {
        float inv = 1.0f / (cntf + 1e-8f);
        a0 *= inv; a1 *= inv; a2 *= inv; a3 *= inv;
        float4 o; o.x = a0; o.y = a1; o.z = a2; o.w = a3;
        *(float4*)(out + (long long)node * 384 + col_off + sub * 4) = o;
        if (xbn) {
            ushort4 h;
            h.x = f2bf(a0); h.y = f2bf(a1); h.z = f2bf(a2); h.w = f2bf(a3);
            *(ushort4*)(xbn + (long long)node * F_ + sub * 4) = h;
        }
    }
}

extern "C" void kernel_launch(void* const* d_in, const int* in_sizes, int n_in,
                              void* d_out, int out_size, void* d_ws, size_t ws_size,
                              hipStream_t stream) {
    const float* x0        = (const float*)d_in[0];
    const int*   edges_raw = (const int*)d_in[1];
    const int*   ne_raw    = (const int*)d_in[2];
    const int*   mask      = (const int*)d_in[3];
    const float* W1        = (const float*)d_in[4];
    const float* b1        = (const float*)d_in[5];
    const float* W2        = (const float*)d_in[6];
    const float* b2        = (const float*)d_in[7];
    float* out = (float*)d_out;
    char* ws = (char*)d_ws;

    unsigned short* xb   = (unsigned short*)ws;                   // B*N*F bf16   = 8 MB
    unsigned short* ebuf = (unsigned short*)(ws + 8388608);       // B*E*F bf16   = 32 MB
    unsigned short* wf   = (unsigned short*)(ws + 41943040);      // 2*128*128    = 64 KB
    int* sender32        = (int*)(ws + 42008576);                 // B*E int32    = 512 KB
    int* pne             = (int*)(ws + 42532864);                 // B*N*K int32  = 2 MB

    conv_sender<<<512, 256, 0, stream>>>(edges_raw, sender32);
    conv_ne<<<2048, 256, 0, stream>>>(ne_raw, mask, pne);
    wprep<<<16, 256, 0, stream>>>(W1, W2, wf);
    prep_x0<<<4096, 256, 0, stream>>>(x0, out, xb);

    // round 1
    edge_kernel<<<2048, 256, 0, stream>>>(xb, sender32, wf, b1, ebuf);
    agg_kernel<<<8192, 256, 0, stream>>>(ebuf, pne, out, xb, 128);
    // round 2
    edge_kernel<<<2048, 256, 0, stream>>>(xb, sender32, wf + 16384, b2, ebuf);
    agg_kernel<<<8192, 256, 0, stream>>>(ebuf, pne, out, nullptr, 256);
}